// Round 1
// baseline (541.148 us; speedup 1.0000x reference)
//
#include <hip/hip_runtime.h>
#include <cstdint>
#include <cstddef>

#define N_NODES 50000
#define N_EDGES 1600000
#define TOT_E   (N_EDGES + N_NODES)
#define IN_DIM  256
#define HC      128
#define NHEAD   4
#define OUT_DIM 64

// ---------------------------------------------------------------------------
// K1: h = x @ W   [N,256] @ [256,128] -> [N,128]  (fp32, LDS-tiled)
// block = 256 threads, tile = 64 rows x 128 cols, thread owns 8 rows x 4 cols
// ---------------------------------------------------------------------------
__global__ __launch_bounds__(256) void k1_gemm(const float* __restrict__ x,
                                               const float* __restrict__ W,
                                               float* __restrict__ h) {
    __shared__ float xs[64 * IN_DIM];  // 64 KB
    const int tid  = threadIdx.x;
    const int row0 = blockIdx.x * 64;

    // Stage x tile (coalesced float4)
    for (int i = tid * 4; i < 64 * IN_DIM; i += 256 * 4) {
        int r  = i >> 8;          // /256
        int c  = i & 255;
        int gr = row0 + r;
        float4 v = make_float4(0.f, 0.f, 0.f, 0.f);
        if (gr < N_NODES) v = *(const float4*)(x + (size_t)gr * IN_DIM + c);
        *(float4*)(xs + i) = v;
    }
    __syncthreads();

    const int colb = (tid & 31) * 4;   // 0..124
    const int rg   = tid >> 5;         // 0..7 (row group of 8)

    float acc[8][4];
    #pragma unroll
    for (int r = 0; r < 8; ++r)
        #pragma unroll
        for (int c = 0; c < 4; ++c) acc[r][c] = 0.f;

    for (int k = 0; k < IN_DIM; k += 4) {
        float4 w0 = *(const float4*)(W + (size_t)(k + 0) * HC + colb);
        float4 w1 = *(const float4*)(W + (size_t)(k + 1) * HC + colb);
        float4 w2 = *(const float4*)(W + (size_t)(k + 2) * HC + colb);
        float4 w3 = *(const float4*)(W + (size_t)(k + 3) * HC + colb);
        #pragma unroll
        for (int r = 0; r < 8; ++r) {
            float4 xv = *(const float4*)(xs + (rg * 8 + r) * IN_DIM + k);
            acc[r][0] += xv.x * w0.x; acc[r][0] += xv.y * w1.x;
            acc[r][0] += xv.z * w2.x; acc[r][0] += xv.w * w3.x;
            acc[r][1] += xv.x * w0.y; acc[r][1] += xv.y * w1.y;
            acc[r][1] += xv.z * w2.y; acc[r][1] += xv.w * w3.y;
            acc[r][2] += xv.x * w0.z; acc[r][2] += xv.y * w1.z;
            acc[r][2] += xv.z * w2.z; acc[r][2] += xv.w * w3.z;
            acc[r][3] += xv.x * w0.w; acc[r][3] += xv.y * w1.w;
            acc[r][3] += xv.z * w2.w; acc[r][3] += xv.w * w3.w;
        }
    }

    #pragma unroll
    for (int r = 0; r < 8; ++r) {
        int row = row0 + rg * 8 + r;
        if (row < N_NODES) {
            float4 v = make_float4(acc[r][0], acc[r][1], acc[r][2], acc[r][3]);
            *(float4*)(h + (size_t)row * HC + colb) = v;
        }
    }
}

// ---------------------------------------------------------------------------
// K2: a_src[n,h] = sum_c h[n,h,c]*att_src[h,c]; same for a_dst
// block = 256 threads = 2 nodes x 128 channels
// ---------------------------------------------------------------------------
__global__ __launch_bounds__(256) void k2_attn(const float* __restrict__ h,
                                               const float* __restrict__ att_src,
                                               const float* __restrict__ att_dst,
                                               float* __restrict__ a_src,
                                               float* __restrict__ a_dst) {
    const int tid  = threadIdx.x;
    const int node = blockIdx.x * 2 + (tid >> 7);
    const int c    = tid & 127;
    float v = h[(size_t)node * HC + c];
    float s = v * att_src[c];
    float d = v * att_dst[c];
    #pragma unroll
    for (int off = 16; off > 0; off >>= 1) {
        s += __shfl_down(s, off, 32);
        d += __shfl_down(d, off, 32);
    }
    if ((c & 31) == 0) {
        a_src[node * NHEAD + (c >> 5)] = s;
        a_dst[node * NHEAD + (c >> 5)] = d;
    }
}

// ---------------------------------------------------------------------------
// K3: count incoming edges per dst (including self loops)
// ---------------------------------------------------------------------------
__global__ __launch_bounds__(256) void k3_count(const int* __restrict__ ei,
                                                int* __restrict__ count) {
    int e = blockIdx.x * 256 + threadIdx.x;
    if (e >= TOT_E) return;
    int dst = (e < N_EDGES) ? ei[N_EDGES + e] : (e - N_EDGES);
    atomicAdd(&count[dst], 1);
}

// ---------------------------------------------------------------------------
// K4: single-block exclusive scan of count -> rowptr  (N=50000, 49 chunks)
// ---------------------------------------------------------------------------
__global__ __launch_bounds__(1024) void k4_scan(const int* __restrict__ count,
                                                int* __restrict__ rowptr) {
    __shared__ int s_wsum[16];
    __shared__ int s_woff[16];
    __shared__ int s_total;
    __shared__ int s_base;
    const int tid  = threadIdx.x;
    const int lane = tid & 63;
    const int wid  = tid >> 6;
    if (tid == 0) s_base = 0;
    __syncthreads();
    for (int start = 0; start < N_NODES; start += 1024) {
        int i = start + tid;
        int v = (i < N_NODES) ? count[i] : 0;
        int inc = v;
        #pragma unroll
        for (int d = 1; d < 64; d <<= 1) {
            int t = __shfl_up(inc, d, 64);
            if (lane >= d) inc += t;
        }
        if (lane == 63) s_wsum[wid] = inc;
        __syncthreads();
        if (tid < 16) {
            int wv   = s_wsum[tid];
            int winc = wv;
            #pragma unroll
            for (int d = 1; d < 16; d <<= 1) {
                int t = __shfl_up(winc, d, 16);
                if (tid >= d) winc += t;
            }
            s_woff[tid] = winc - wv;
            if (tid == 15) s_total = winc;
        }
        __syncthreads();
        if (i < N_NODES) rowptr[i] = s_base + s_woff[wid] + inc - v;
        __syncthreads();
        if (tid == 0) s_base += s_total;
        __syncthreads();
    }
    if (tid == 0) rowptr[N_NODES] = s_base;
}

// ---------------------------------------------------------------------------
// K5: scatter edges into CSR slots (src index per incoming edge of dst)
// ---------------------------------------------------------------------------
__global__ __launch_bounds__(256) void k5_fill(const int* __restrict__ ei,
                                               const int* __restrict__ rowptr,
                                               int* __restrict__ cursor,
                                               int* __restrict__ csr_src) {
    int e = blockIdx.x * 256 + threadIdx.x;
    if (e >= TOT_E) return;
    int src, dst;
    if (e < N_EDGES) { src = ei[e]; dst = ei[N_EDGES + e]; }
    else             { src = e - N_EDGES; dst = src; }
    int pos = atomicAdd(&cursor[dst], 1);
    csr_src[rowptr[dst] + pos] = src;
}

// ---------------------------------------------------------------------------
// K6: per-node online-softmax aggregation + bias + ELU
// block = 64 threads (1 wave) per node; lane owns 2 channels (float2)
// ---------------------------------------------------------------------------
__global__ __launch_bounds__(64) void k6_agg(const float* __restrict__ h,
                                             const float* __restrict__ a_src,
                                             const float* __restrict__ a_dst,
                                             const int* __restrict__ rowptr,
                                             const int* __restrict__ csr_src,
                                             const float* __restrict__ bias,
                                             float* __restrict__ act) {
    const int node = blockIdx.x;
    const int lane = threadIdx.x;
    const int c0   = lane << 1;
    const int head = lane >> 4;

    const float ad  = a_dst[node * NHEAD + head];
    const int   beg = rowptr[node];
    const int   end = rowptr[node + 1];

    float m = -__builtin_inff();
    float l = 0.f, acc0 = 0.f, acc1 = 0.f;

    for (int p = beg; p < end; ++p) {
        int src = csr_src[p];
        float e = a_src[src * NHEAD + head] + ad;
        e = (e > 0.f) ? e : 0.2f * e;                 // LeakyReLU(0.2)
        float mn = fmaxf(m, e);
        float sc = __expf(m - mn);                    // exp(-inf)=0 first iter
        float w  = __expf(e - mn);
        float2 hv = *(const float2*)(h + (size_t)src * HC + c0);
        l    = l * sc + w;
        acc0 = fmaf(acc0, sc, w * hv.x);
        acc1 = fmaf(acc1, sc, w * hv.y);
        m = mn;
    }

    float inv = 1.f / l;                              // self loop => l > 0
    float o0 = acc0 * inv + bias[c0];
    float o1 = acc1 * inv + bias[c0 + 1];
    o0 = (o0 > 0.f) ? o0 : (__expf(o0) - 1.f);        // ELU
    o1 = (o1 > 0.f) ? o1 : (__expf(o1) - 1.f);
    *(float2*)(act + (size_t)node * HC + c0) = make_float2(o0, o1);
}

// ---------------------------------------------------------------------------
// K7: out = act @ lin_W + lin_b   [N,128] @ [128,64]
// block = 512 threads = 32 nodes x 16 col-quads; lin_W + rows staged in LDS
// ---------------------------------------------------------------------------
__global__ __launch_bounds__(512) void k7_out(const float* __restrict__ act,
                                              const float* __restrict__ linW,
                                              const float* __restrict__ linb,
                                              float* __restrict__ out) {
    __shared__ float sW[HC * OUT_DIM];   // 32 KB
    __shared__ float srow[32 * HC];      // 16 KB
    const int tid   = threadIdx.x;
    const int node0 = blockIdx.x * 32;

    for (int i = tid * 4; i < HC * OUT_DIM; i += 512 * 4)
        *(float4*)(sW + i) = *(const float4*)(linW + i);
    for (int i = tid * 4; i < 32 * HC; i += 512 * 4) {
        int r = i >> 7;
        int node = node0 + r;
        float4 v = make_float4(0.f, 0.f, 0.f, 0.f);
        if (node < N_NODES) v = *(const float4*)(act + (size_t)node * HC + (i & 127));
        *(float4*)(srow + i) = v;
    }
    __syncthreads();

    const int r    = tid >> 4;          // 0..31
    const int colb = (tid & 15) << 2;   // 0..60
    float4 acc = *(const float4*)(linb + colb);
    const float* rp = srow + r * HC;

    #pragma unroll
    for (int k = 0; k < HC; k += 4) {
        float4 xv = *(const float4*)(rp + k);
        float4 w0 = *(const float4*)(sW + (k + 0) * OUT_DIM + colb);
        float4 w1 = *(const float4*)(sW + (k + 1) * OUT_DIM + colb);
        float4 w2 = *(const float4*)(sW + (k + 2) * OUT_DIM + colb);
        float4 w3 = *(const float4*)(sW + (k + 3) * OUT_DIM + colb);
        acc.x += xv.x * w0.x; acc.x += xv.y * w1.x; acc.x += xv.z * w2.x; acc.x += xv.w * w3.x;
        acc.y += xv.x * w0.y; acc.y += xv.y * w1.y; acc.y += xv.z * w2.y; acc.y += xv.w * w3.y;
        acc.z += xv.x * w0.z; acc.z += xv.y * w1.z; acc.z += xv.z * w2.z; acc.z += xv.w * w3.z;
        acc.w += xv.x * w0.w; acc.w += xv.y * w1.w; acc.w += xv.z * w2.w; acc.w += xv.w * w3.w;
    }

    int node = node0 + r;
    if (node < N_NODES)
        *(float4*)(out + (size_t)node * OUT_DIM + colb) = acc;
}

// ---------------------------------------------------------------------------
extern "C" void kernel_launch(void* const* d_in, const int* in_sizes, int n_in,
                              void* d_out, int out_size, void* d_ws, size_t ws_size,
                              hipStream_t stream) {
    (void)in_sizes; (void)n_in; (void)out_size; (void)ws_size;
    const float* x       = (const float*)d_in[0];
    const int*   ei      = (const int*)d_in[1];
    const float* W       = (const float*)d_in[2];
    const float* att_src = (const float*)d_in[3];
    const float* att_dst = (const float*)d_in[4];
    const float* bias    = (const float*)d_in[5];
    const float* linW    = (const float*)d_in[6];
    const float* linb    = (const float*)d_in[7];
    float*       out     = (float*)d_out;

    char*  ws  = (char*)d_ws;
    size_t off = 0;
    auto alloc = [&](size_t bytes) -> void* {
        void* p = ws + off;
        off += (bytes + 255) & ~(size_t)255;
        return p;
    };
    float* h      = (float*)alloc((size_t)N_NODES * HC * 4);
    float* act    = (float*)alloc((size_t)N_NODES * HC * 4);
    float* a_src  = (float*)alloc((size_t)N_NODES * NHEAD * 4);
    float* a_dst  = (float*)alloc((size_t)N_NODES * NHEAD * 4);
    int*   count  = (int*)alloc((size_t)N_NODES * 4);
    int*   cursor = (int*)alloc((size_t)N_NODES * 4);
    int*   rowptr = (int*)alloc((size_t)(N_NODES + 1) * 4);
    int*   csr    = (int*)alloc((size_t)TOT_E * 4);

    hipMemsetAsync(count, 0, (size_t)N_NODES * 4, stream);
    hipMemsetAsync(cursor, 0, (size_t)N_NODES * 4, stream);

    k1_gemm<<<(N_NODES + 63) / 64, 256, 0, stream>>>(x, W, h);
    k2_attn<<<N_NODES / 2, 256, 0, stream>>>(h, att_src, att_dst, a_src, a_dst);
    k3_count<<<(TOT_E + 255) / 256, 256, 0, stream>>>(ei, count);
    k4_scan<<<1, 1024, 0, stream>>>(count, rowptr);
    k5_fill<<<(TOT_E + 255) / 256, 256, 0, stream>>>(ei, rowptr, cursor, csr);
    k6_agg<<<N_NODES, 64, 0, stream>>>(h, a_src, a_dst, rowptr, csr, bias, act);
    k7_out<<<(N_NODES + 31) / 32, 512, 0, stream>>>(act, linW, linb, out);
}

// Round 2
// 444.726 us; speedup vs baseline: 1.2168x; 1.2168x over previous
//
#include <hip/hip_runtime.h>
#include <cstdint>
#include <cstddef>

#define N_NODES 50000
#define N_EDGES 1600000
#define TOT_E   (N_EDGES + N_NODES)
#define IN_DIM  256
#define HC      128
#define NHEAD   4
#define OUT_DIM 64

static __device__ __forceinline__ uint16_t f2bf(float f) {
    uint32_t u = __float_as_uint(f);
    uint32_t r = (u + 0x7fffu + ((u >> 16) & 1u)) >> 16;   // RNE
    return (uint16_t)r;
}
static __device__ __forceinline__ float bf_lo(uint32_t u) {
    return __uint_as_float(u << 16);
}
static __device__ __forceinline__ float bf_hi(uint32_t u) {
    return __uint_as_float(u & 0xffff0000u);
}

// ---------------------------------------------------------------------------
// K1: h = x @ W  [N,256]@[256,128]; writes h as bf16 ONLY (gather payload),
// and fuses the attention halves a_src/a_dst = h · att_{src,dst} (fp32, from
// the in-register accumulator tile, per-head 8-lane shuffle reduction).
// block = 256 thr, tile = 64 rows x 128 cols, thread owns 8 rows x 4 cols.
// ---------------------------------------------------------------------------
__global__ __launch_bounds__(256) void k1_gemm(const float* __restrict__ x,
                                               const float* __restrict__ W,
                                               const float* __restrict__ att_src,
                                               const float* __restrict__ att_dst,
                                               uint16_t* __restrict__ hb,
                                               float* __restrict__ a_src,
                                               float* __restrict__ a_dst) {
    __shared__ float xs[64 * IN_DIM];  // 64 KB
    const int tid  = threadIdx.x;
    const int row0 = blockIdx.x * 64;

    for (int i = tid * 4; i < 64 * IN_DIM; i += 256 * 4) {
        int r  = i >> 8;
        int c  = i & 255;
        int gr = row0 + r;
        float4 v = make_float4(0.f, 0.f, 0.f, 0.f);
        if (gr < N_NODES) v = *(const float4*)(x + (size_t)gr * IN_DIM + c);
        *(float4*)(xs + i) = v;
    }
    __syncthreads();

    const int colb = (tid & 31) * 4;   // 0..124 (within one head)
    const int rg   = tid >> 5;         // 0..7

    float acc[8][4];
    #pragma unroll
    for (int r = 0; r < 8; ++r)
        #pragma unroll
        for (int c = 0; c < 4; ++c) acc[r][c] = 0.f;

    for (int k = 0; k < IN_DIM; k += 4) {
        float4 w0 = *(const float4*)(W + (size_t)(k + 0) * HC + colb);
        float4 w1 = *(const float4*)(W + (size_t)(k + 1) * HC + colb);
        float4 w2 = *(const float4*)(W + (size_t)(k + 2) * HC + colb);
        float4 w3 = *(const float4*)(W + (size_t)(k + 3) * HC + colb);
        #pragma unroll
        for (int r = 0; r < 8; ++r) {
            float4 xv = *(const float4*)(xs + (rg * 8 + r) * IN_DIM + k);
            acc[r][0] += xv.x * w0.x; acc[r][0] += xv.y * w1.x;
            acc[r][0] += xv.z * w2.x; acc[r][0] += xv.w * w3.x;
            acc[r][1] += xv.x * w0.y; acc[r][1] += xv.y * w1.y;
            acc[r][1] += xv.z * w2.y; acc[r][1] += xv.w * w3.y;
            acc[r][2] += xv.x * w0.z; acc[r][2] += xv.y * w1.z;
            acc[r][2] += xv.z * w2.z; acc[r][2] += xv.w * w3.z;
            acc[r][3] += xv.x * w0.w; acc[r][3] += xv.y * w1.w;
            acc[r][3] += xv.z * w2.w; acc[r][3] += xv.w * w3.w;
        }
    }

    // bf16 store of the h tile
    #pragma unroll
    for (int r = 0; r < 8; ++r) {
        int row = row0 + rg * 8 + r;
        if (row < N_NODES) {
            uint32_t lo = (uint32_t)f2bf(acc[r][0]) | ((uint32_t)f2bf(acc[r][1]) << 16);
            uint32_t hi = (uint32_t)f2bf(acc[r][2]) | ((uint32_t)f2bf(acc[r][3]) << 16);
            *(uint2*)(hb + (size_t)row * HC + colb) = make_uint2(lo, hi);
        }
    }

    // fused attention halves (fp32): per-thread partial dot over its 4 cols,
    // then reduce across the 8 lanes covering one head (xor 1,2,4).
    float4 as4 = *(const float4*)(att_src + colb);
    float4 ad4 = *(const float4*)(att_dst + colb);
    const int head = (tid & 31) >> 3;
    #pragma unroll
    for (int r = 0; r < 8; ++r) {
        float ps = acc[r][0] * as4.x + acc[r][1] * as4.y +
                   acc[r][2] * as4.z + acc[r][3] * as4.w;
        float pd = acc[r][0] * ad4.x + acc[r][1] * ad4.y +
                   acc[r][2] * ad4.z + acc[r][3] * ad4.w;
        #pragma unroll
        for (int off = 1; off < 8; off <<= 1) {
            ps += __shfl_xor(ps, off, 64);
            pd += __shfl_xor(pd, off, 64);
        }
        int row = row0 + rg * 8 + r;
        if ((tid & 7) == 0 && row < N_NODES) {
            a_src[row * NHEAD + head] = ps;
            a_dst[row * NHEAD + head] = pd;
        }
    }
}

// ---------------------------------------------------------------------------
// K3: count incoming edges per dst (incl. self loops)
// ---------------------------------------------------------------------------
__global__ __launch_bounds__(256) void k3_count(const int* __restrict__ ei,
                                                int* __restrict__ count) {
    int e = blockIdx.x * 256 + threadIdx.x;
    if (e >= TOT_E) return;
    int dst = (e < N_EDGES) ? ei[N_EDGES + e] : (e - N_EDGES);
    atomicAdd(&count[dst], 1);
}

// ---------------------------------------------------------------------------
// Hierarchical exclusive scan: kA per-block scan, kB scan of 196 partials,
// kC add base -> rowptr + cursor (absolute).
// ---------------------------------------------------------------------------
#define SCAN_NB ((N_NODES + 255) / 256)

__global__ __launch_bounds__(256) void kA_blockscan(const int* __restrict__ count,
                                                    int* __restrict__ excl,
                                                    int* __restrict__ blksum) {
    __shared__ int ws[4];
    const int tid  = threadIdx.x;
    const int lane = tid & 63;
    const int wid  = tid >> 6;
    int i = blockIdx.x * 256 + tid;
    int v = (i < N_NODES) ? count[i] : 0;
    int inc = v;
    #pragma unroll
    for (int d = 1; d < 64; d <<= 1) {
        int t = __shfl_up(inc, d, 64);
        if (lane >= d) inc += t;
    }
    if (lane == 63) ws[wid] = inc;
    __syncthreads();
    int wo = 0;
    for (int w = 0; w < wid; ++w) wo += ws[w];
    if (i < N_NODES) excl[i] = wo + inc - v;
    if (tid == 255) blksum[blockIdx.x] = wo + inc;
}

__global__ __launch_bounds__(256) void kB_scansums(const int* __restrict__ blksum,
                                                   int* __restrict__ blkoff) {
    __shared__ int ws[4];
    const int tid  = threadIdx.x;
    const int lane = tid & 63;
    const int wid  = tid >> 6;
    int v = (tid < SCAN_NB) ? blksum[tid] : 0;
    int inc = v;
    #pragma unroll
    for (int d = 1; d < 64; d <<= 1) {
        int t = __shfl_up(inc, d, 64);
        if (lane >= d) inc += t;
    }
    if (lane == 63) ws[wid] = inc;
    __syncthreads();
    int wo = 0;
    for (int w = 0; w < wid; ++w) wo += ws[w];
    if (tid < SCAN_NB) blkoff[tid] = wo + inc - v;
}

__global__ __launch_bounds__(256) void kC_addbase(const int* __restrict__ excl,
                                                  const int* __restrict__ blkoff,
                                                  int* __restrict__ rowptr,
                                                  int* __restrict__ cursor) {
    int i = blockIdx.x * 256 + threadIdx.x;
    if (i < N_NODES) {
        int base = excl[i] + blkoff[blockIdx.x];
        rowptr[i] = base;
        cursor[i] = base;
    }
    if (i == 0) rowptr[N_NODES] = TOT_E;
}

// ---------------------------------------------------------------------------
// K5: scatter edges into CSR slots (cursor holds absolute position)
// ---------------------------------------------------------------------------
__global__ __launch_bounds__(256) void k5_fill(const int* __restrict__ ei,
                                               int* __restrict__ cursor,
                                               int* __restrict__ csr_src) {
    int e = blockIdx.x * 256 + threadIdx.x;
    if (e >= TOT_E) return;
    int src, dst;
    if (e < N_EDGES) { src = ei[e]; dst = ei[N_EDGES + e]; }
    else             { src = e - N_EDGES; dst = src; }
    int pos = atomicAdd(&cursor[dst], 1);
    csr_src[pos] = src;
}

// ---------------------------------------------------------------------------
// K6: per-node softmax aggregation (no max subtraction: |e| < ~4 by data
// scale, exp cannot overflow; mathematically identical to ref) + bias + ELU.
// h gathered in bf16 (uint32 = 2 channels per lane). Unroll-4 for MLP.
// block = 64 threads (1 wave) per node.
// ---------------------------------------------------------------------------
__global__ __launch_bounds__(64) void k6_agg(const uint32_t* __restrict__ hb32,
                                             const float* __restrict__ a_src,
                                             const float* __restrict__ a_dst,
                                             const int* __restrict__ rowptr,
                                             const int* __restrict__ csr_src,
                                             const float* __restrict__ bias,
                                             float* __restrict__ act) {
    const int node = blockIdx.x;
    const int lane = threadIdx.x;
    const int c0   = lane << 1;
    const int head = lane >> 4;

    const float ad  = a_dst[node * NHEAD + head];
    const int   beg = rowptr[node];
    const int   end = rowptr[node + 1];

    float l = 0.f, acc0 = 0.f, acc1 = 0.f;

    int p = beg;
    for (; p + 4 <= end; p += 4) {
        int s0 = csr_src[p + 0];
        int s1 = csr_src[p + 1];
        int s2 = csr_src[p + 2];
        int s3 = csr_src[p + 3];
        float e0 = a_src[s0 * NHEAD + head] + ad;
        float e1 = a_src[s1 * NHEAD + head] + ad;
        float e2 = a_src[s2 * NHEAD + head] + ad;
        float e3 = a_src[s3 * NHEAD + head] + ad;
        uint32_t u0 = hb32[(size_t)s0 * 64 + lane];
        uint32_t u1 = hb32[(size_t)s1 * 64 + lane];
        uint32_t u2 = hb32[(size_t)s2 * 64 + lane];
        uint32_t u3 = hb32[(size_t)s3 * 64 + lane];
        e0 = (e0 > 0.f) ? e0 : 0.2f * e0;
        e1 = (e1 > 0.f) ? e1 : 0.2f * e1;
        e2 = (e2 > 0.f) ? e2 : 0.2f * e2;
        e3 = (e3 > 0.f) ? e3 : 0.2f * e3;
        float w0 = __expf(e0), w1 = __expf(e1);
        float w2 = __expf(e2), w3 = __expf(e3);
        l += (w0 + w1) + (w2 + w3);
        acc0 = fmaf(w0, bf_lo(u0), acc0);
        acc1 = fmaf(w0, bf_hi(u0), acc1);
        acc0 = fmaf(w1, bf_lo(u1), acc0);
        acc1 = fmaf(w1, bf_hi(u1), acc1);
        acc0 = fmaf(w2, bf_lo(u2), acc0);
        acc1 = fmaf(w2, bf_hi(u2), acc1);
        acc0 = fmaf(w3, bf_lo(u3), acc0);
        acc1 = fmaf(w3, bf_hi(u3), acc1);
    }
    for (; p < end; ++p) {
        int s = csr_src[p];
        float e = a_src[s * NHEAD + head] + ad;
        e = (e > 0.f) ? e : 0.2f * e;
        float w = __expf(e);
        uint32_t u = hb32[(size_t)s * 64 + lane];
        l += w;
        acc0 = fmaf(w, bf_lo(u), acc0);
        acc1 = fmaf(w, bf_hi(u), acc1);
    }

    float inv = 1.f / l;                       // self loop => l > 0
    float o0 = acc0 * inv + bias[c0];
    float o1 = acc1 * inv + bias[c0 + 1];
    o0 = (o0 > 0.f) ? o0 : (__expf(o0) - 1.f); // ELU
    o1 = (o1 > 0.f) ? o1 : (__expf(o1) - 1.f);
    *(float2*)(act + (size_t)node * HC + c0) = make_float2(o0, o1);
}

// ---------------------------------------------------------------------------
// K7: out = act @ lin_W + lin_b   [N,128] @ [128,64]
// ---------------------------------------------------------------------------
__global__ __launch_bounds__(512) void k7_out(const float* __restrict__ act,
                                              const float* __restrict__ linW,
                                              const float* __restrict__ linb,
                                              float* __restrict__ out) {
    __shared__ float sW[HC * OUT_DIM];   // 32 KB
    __shared__ float srow[32 * HC];      // 16 KB
    const int tid   = threadIdx.x;
    const int node0 = blockIdx.x * 32;

    for (int i = tid * 4; i < HC * OUT_DIM; i += 512 * 4)
        *(float4*)(sW + i) = *(const float4*)(linW + i);
    for (int i = tid * 4; i < 32 * HC; i += 512 * 4) {
        int r = i >> 7;
        int node = node0 + r;
        float4 v = make_float4(0.f, 0.f, 0.f, 0.f);
        if (node < N_NODES) v = *(const float4*)(act + (size_t)node * HC + (i & 127));
        *(float4*)(srow + i) = v;
    }
    __syncthreads();

    const int r    = tid >> 4;
    const int colb = (tid & 15) << 2;
    float4 acc = *(const float4*)(linb + colb);
    const float* rp = srow + r * HC;

    #pragma unroll
    for (int k = 0; k < HC; k += 4) {
        float4 xv = *(const float4*)(rp + k);
        float4 w0 = *(const float4*)(sW + (k + 0) * OUT_DIM + colb);
        float4 w1 = *(const float4*)(sW + (k + 1) * OUT_DIM + colb);
        float4 w2 = *(const float4*)(sW + (k + 2) * OUT_DIM + colb);
        float4 w3 = *(const float4*)(sW + (k + 3) * OUT_DIM + colb);
        acc.x += xv.x * w0.x; acc.x += xv.y * w1.x; acc.x += xv.z * w2.x; acc.x += xv.w * w3.x;
        acc.y += xv.x * w0.y; acc.y += xv.y * w1.y; acc.y += xv.z * w2.y; acc.y += xv.w * w3.y;
        acc.z += xv.x * w0.z; acc.z += xv.y * w1.z; acc.z += xv.z * w2.z; acc.z += xv.w * w3.z;
        acc.w += xv.x * w0.w; acc.w += xv.y * w1.w; acc.w += xv.z * w2.w; acc.w += xv.w * w3.w;
    }

    int node = node0 + r;
    if (node < N_NODES)
        *(float4*)(out + (size_t)node * OUT_DIM + colb) = acc;
}

// ---------------------------------------------------------------------------
extern "C" void kernel_launch(void* const* d_in, const int* in_sizes, int n_in,
                              void* d_out, int out_size, void* d_ws, size_t ws_size,
                              hipStream_t stream) {
    (void)in_sizes; (void)n_in; (void)out_size; (void)ws_size;
    const float* x       = (const float*)d_in[0];
    const int*   ei      = (const int*)d_in[1];
    const float* W       = (const float*)d_in[2];
    const float* att_src = (const float*)d_in[3];
    const float* att_dst = (const float*)d_in[4];
    const float* bias    = (const float*)d_in[5];
    const float* linW    = (const float*)d_in[6];
    const float* linb    = (const float*)d_in[7];
    float*       out     = (float*)d_out;

    char*  ws  = (char*)d_ws;
    size_t off = 0;
    auto alloc = [&](size_t bytes) -> void* {
        void* p = ws + off;
        off += (bytes + 255) & ~(size_t)255;
        return p;
    };
    uint16_t* hb     = (uint16_t*)alloc((size_t)N_NODES * HC * 2);
    float*    act    = (float*)alloc((size_t)N_NODES * HC * 4);
    float*    a_src  = (float*)alloc((size_t)N_NODES * NHEAD * 4);
    float*    a_dst  = (float*)alloc((size_t)N_NODES * NHEAD * 4);
    int*      count  = (int*)alloc((size_t)N_NODES * 4);
    int*      cursor = (int*)alloc((size_t)N_NODES * 4);
    int*      rowptr = (int*)alloc((size_t)(N_NODES + 1) * 4);
    int*      excl   = (int*)alloc((size_t)N_NODES * 4);
    int*      blksum = (int*)alloc((size_t)SCAN_NB * 4);
    int*      blkoff = (int*)alloc((size_t)SCAN_NB * 4);
    int*      csr    = (int*)alloc((size_t)TOT_E * 4);

    hipMemsetAsync(count, 0, (size_t)N_NODES * 4, stream);

    k1_gemm<<<(N_NODES + 63) / 64, 256, 0, stream>>>(x, W, att_src, att_dst,
                                                     hb, a_src, a_dst);
    k3_count<<<(TOT_E + 255) / 256, 256, 0, stream>>>(ei, count);
    kA_blockscan<<<SCAN_NB, 256, 0, stream>>>(count, excl, blksum);
    kB_scansums<<<1, 256, 0, stream>>>(blksum, blkoff);
    kC_addbase<<<SCAN_NB, 256, 0, stream>>>(excl, blkoff, rowptr, cursor);
    k5_fill<<<(TOT_E + 255) / 256, 256, 0, stream>>>(ei, cursor, csr);
    k6_agg<<<N_NODES, 64, 0, stream>>>((const uint32_t*)hb, a_src, a_dst,
                                       rowptr, csr, bias, act);
    k7_out<<<(N_NODES + 31) / 32, 512, 0, stream>>>(act, linW, linb, out);
}

// Round 3
// 306.919 us; speedup vs baseline: 1.7632x; 1.4490x over previous
//
#include <hip/hip_runtime.h>
#include <cstdint>
#include <cstddef>

#define N_NODES 50000
#define N_EDGES 1600000
#define TOT_E   (N_EDGES + N_NODES)
#define IN_DIM  256
#define HC      128
#define NHEAD   4
#define OUT_DIM 64

// bucket-radix CSR build
#define SHIFT   7
#define BSZ     128                       // nodes per bucket
#define NBUK    ((N_NODES + BSZ - 1) / BSZ)   // 391
#define CHUNK   8192
#define EPT     32                        // edges per thread (CHUNK/256)
#define NCHUNK  ((TOT_E + CHUNK - 1) / CHUNK) // 202
#define CAP     5120                      // bucket LDS capacity (mean 4224, +13 sd)

static __device__ __forceinline__ uint16_t f2bf(float f) {
    uint32_t u = __float_as_uint(f);
    uint32_t r = (u + 0x7fffu + ((u >> 16) & 1u)) >> 16;   // RNE
    return (uint16_t)r;
}
static __device__ __forceinline__ float bf_lo(uint32_t u) {
    return __uint_as_float(u << 16);
}
static __device__ __forceinline__ float bf_hi(uint32_t u) {
    return __uint_as_float(u & 0xffff0000u);
}

// ---------------------------------------------------------------------------
// K1: h = x @ W  [N,256]@[256,128]; writes h as bf16 (gather payload) and
// fuses a_src/a_dst = h · att_{src,dst} (fp32 from the register tile).
// ---------------------------------------------------------------------------
__global__ __launch_bounds__(256) void k1_gemm(const float* __restrict__ x,
                                               const float* __restrict__ W,
                                               const float* __restrict__ att_src,
                                               const float* __restrict__ att_dst,
                                               uint16_t* __restrict__ hb,
                                               float* __restrict__ a_src,
                                               float* __restrict__ a_dst) {
    __shared__ float xs[64 * IN_DIM];  // 64 KB
    const int tid  = threadIdx.x;
    const int row0 = blockIdx.x * 64;

    for (int i = tid * 4; i < 64 * IN_DIM; i += 256 * 4) {
        int r  = i >> 8;
        int c  = i & 255;
        int gr = row0 + r;
        float4 v = make_float4(0.f, 0.f, 0.f, 0.f);
        if (gr < N_NODES) v = *(const float4*)(x + (size_t)gr * IN_DIM + c);
        *(float4*)(xs + i) = v;
    }
    __syncthreads();

    const int colb = (tid & 31) * 4;   // 0..124
    const int rg   = tid >> 5;         // 0..7

    float acc[8][4];
    #pragma unroll
    for (int r = 0; r < 8; ++r)
        #pragma unroll
        for (int c = 0; c < 4; ++c) acc[r][c] = 0.f;

    for (int k = 0; k < IN_DIM; k += 4) {
        float4 w0 = *(const float4*)(W + (size_t)(k + 0) * HC + colb);
        float4 w1 = *(const float4*)(W + (size_t)(k + 1) * HC + colb);
        float4 w2 = *(const float4*)(W + (size_t)(k + 2) * HC + colb);
        float4 w3 = *(const float4*)(W + (size_t)(k + 3) * HC + colb);
        #pragma unroll
        for (int r = 0; r < 8; ++r) {
            float4 xv = *(const float4*)(xs + (rg * 8 + r) * IN_DIM + k);
            acc[r][0] += xv.x * w0.x; acc[r][0] += xv.y * w1.x;
            acc[r][0] += xv.z * w2.x; acc[r][0] += xv.w * w3.x;
            acc[r][1] += xv.x * w0.y; acc[r][1] += xv.y * w1.y;
            acc[r][1] += xv.z * w2.y; acc[r][1] += xv.w * w3.y;
            acc[r][2] += xv.x * w0.z; acc[r][2] += xv.y * w1.z;
            acc[r][2] += xv.z * w2.z; acc[r][2] += xv.w * w3.z;
            acc[r][3] += xv.x * w0.w; acc[r][3] += xv.y * w1.w;
            acc[r][3] += xv.z * w2.w; acc[r][3] += xv.w * w3.w;
        }
    }

    #pragma unroll
    for (int r = 0; r < 8; ++r) {
        int row = row0 + rg * 8 + r;
        if (row < N_NODES) {
            uint32_t lo = (uint32_t)f2bf(acc[r][0]) | ((uint32_t)f2bf(acc[r][1]) << 16);
            uint32_t hi = (uint32_t)f2bf(acc[r][2]) | ((uint32_t)f2bf(acc[r][3]) << 16);
            *(uint2*)(hb + (size_t)row * HC + colb) = make_uint2(lo, hi);
        }
    }

    float4 as4 = *(const float4*)(att_src + colb);
    float4 ad4 = *(const float4*)(att_dst + colb);
    const int head = (tid & 31) >> 3;
    #pragma unroll
    for (int r = 0; r < 8; ++r) {
        float ps = acc[r][0] * as4.x + acc[r][1] * as4.y +
                   acc[r][2] * as4.z + acc[r][3] * as4.w;
        float pd = acc[r][0] * ad4.x + acc[r][1] * ad4.y +
                   acc[r][2] * ad4.z + acc[r][3] * ad4.w;
        #pragma unroll
        for (int off = 1; off < 8; off <<= 1) {
            ps += __shfl_xor(ps, off, 64);
            pd += __shfl_xor(pd, off, 64);
        }
        int row = row0 + rg * 8 + r;
        if ((tid & 7) == 0 && row < N_NODES) {
            a_src[row * NHEAD + head] = ps;
            a_dst[row * NHEAD + head] = pd;
        }
    }
}

// ---------------------------------------------------------------------------
// P1: bucket histogram (block-aggregated; 79K global atomics total)
// ---------------------------------------------------------------------------
__global__ __launch_bounds__(256) void p1_hist(const int* __restrict__ ei,
                                               int* __restrict__ gcount) {
    __shared__ int hist[NBUK];
    const int tid = threadIdx.x;
    for (int i = tid; i < NBUK; i += 256) hist[i] = 0;
    __syncthreads();
    const int base = blockIdx.x * CHUNK;
    #pragma unroll 4
    for (int k = 0; k < EPT; ++k) {
        int e = base + k * 256 + tid;
        if (e < TOT_E) {
            int dst = (e < N_EDGES) ? ei[N_EDGES + e] : (e - N_EDGES);
            atomicAdd(&hist[dst >> SHIFT], 1);
        }
    }
    __syncthreads();
    for (int i = tid; i < NBUK; i += 256)
        if (hist[i]) atomicAdd(&gcount[i], hist[i]);
}

// ---------------------------------------------------------------------------
// P2: 1-block scan of NBUK bucket counts -> bases + cursors
// ---------------------------------------------------------------------------
__global__ __launch_bounds__(512) void p2_scan(const int* __restrict__ gcount,
                                               int* __restrict__ gcur,
                                               int* __restrict__ bbase,
                                               int* __restrict__ rowptr) {
    __shared__ int ws[8];
    const int tid  = threadIdx.x;
    const int lane = tid & 63;
    const int wid  = tid >> 6;
    int v = (tid < NBUK) ? gcount[tid] : 0;
    int inc = v;
    #pragma unroll
    for (int d = 1; d < 64; d <<= 1) {
        int t = __shfl_up(inc, d, 64);
        if (lane >= d) inc += t;
    }
    if (lane == 63) ws[wid] = inc;
    __syncthreads();
    int wo = 0;
    for (int w = 0; w < wid; ++w) wo += ws[w];
    if (tid < NBUK) {
        int ex = wo + inc - v;
        gcur[tid]  = ex;
        bbase[tid] = ex;
    }
    if (tid == 0) { bbase[NBUK] = TOT_E; rowptr[N_NODES] = TOT_E; }
}

// ---------------------------------------------------------------------------
// P3: bin edges into bucket regions as packed words
// word = src(16) | dstlocal(7)<<16 | bucket(9)<<23
// ---------------------------------------------------------------------------
__global__ __launch_bounds__(256) void p3_bin(const int* __restrict__ ei,
                                              int* __restrict__ gcur,
                                              uint32_t* __restrict__ binned) {
    __shared__ int hist[NBUK];
    __shared__ int lcur[NBUK];
    const int tid = threadIdx.x;
    for (int i = tid; i < NBUK; i += 256) hist[i] = 0;
    __syncthreads();

    uint32_t wreg[EPT];
    const int base = blockIdx.x * CHUNK;
    #pragma unroll
    for (int k = 0; k < EPT; ++k) {
        int e = base + k * 256 + tid;
        uint32_t word = 0xFFFFFFFFu;
        if (e < TOT_E) {
            int src, dst;
            if (e < N_EDGES) { src = ei[e]; dst = ei[N_EDGES + e]; }
            else             { src = e - N_EDGES; dst = src; }
            int b = dst >> SHIFT;
            word = (uint32_t)src | ((uint32_t)(dst & (BSZ - 1)) << 16)
                 | ((uint32_t)b << 23);
            atomicAdd(&hist[b], 1);
        }
        wreg[k] = word;
    }
    __syncthreads();
    for (int i = tid; i < NBUK; i += 256) {
        int c = hist[i];
        lcur[i] = c ? atomicAdd(&gcur[i], c) : 0;
    }
    __syncthreads();
    #pragma unroll
    for (int k = 0; k < EPT; ++k) {
        uint32_t word = wreg[k];
        if (word != 0xFFFFFFFFu) {
            int b = (int)(word >> 23);
            int pos = atomicAdd(&lcur[b], 1);
            binned[pos] = word;
        }
    }
}

// ---------------------------------------------------------------------------
// P4: per-bucket (1 block): LDS stage + 128-node count/scan -> rowptr + csr
// All global writes confined to this block's contiguous region (one XCD).
// ---------------------------------------------------------------------------
__global__ __launch_bounds__(256) void p4_csr(const uint32_t* __restrict__ binned,
                                              const int* __restrict__ bbase,
                                              int* __restrict__ rowptr,
                                              int* __restrict__ csr_src) {
    __shared__ uint32_t ew[CAP];
    __shared__ int ncnt[BSZ];
    __shared__ int ncur[BSZ];
    __shared__ int wtot;
    const int b    = blockIdx.x;
    const int base = bbase[b];
    const int cnt  = bbase[b + 1] - base;
    const int tid  = threadIdx.x;

    for (int i = tid; i < BSZ; i += 256) ncnt[i] = 0;
    __syncthreads();

    const bool fit = (cnt <= CAP);
    for (int i = tid; i < cnt; i += 256) {
        uint32_t word = binned[base + i];
        if (fit) ew[i] = word;
        atomicAdd(&ncnt[(word >> 16) & (BSZ - 1)], 1);
    }
    __syncthreads();

    int v = 0, inc = 0;
    if (tid < BSZ) {
        v = ncnt[tid];
        inc = v;
        int lane = tid & 63;
        #pragma unroll
        for (int d = 1; d < 64; d <<= 1) {
            int t = __shfl_up(inc, d, 64);
            if (lane >= d) inc += t;
        }
        if (tid == 63) wtot = inc;
    }
    __syncthreads();
    if (tid < BSZ) {
        int ex = inc - v + ((tid >= 64) ? wtot : 0);
        int node = b * BSZ + tid;
        if (node < N_NODES) rowptr[node] = base + ex;
        ncur[tid] = ex;
    }
    __syncthreads();

    for (int i = tid; i < cnt; i += 256) {
        uint32_t word = fit ? ew[i] : binned[base + i];
        int local = (word >> 16) & (BSZ - 1);
        int r = atomicAdd(&ncur[local], 1);
        csr_src[base + r] = (int)(word & 0xFFFFu);
    }
}

// ---------------------------------------------------------------------------
// K6: per-node softmax aggregation (no max subtraction; |e| small by data
// scale, mathematically identical to ref) + bias + ELU. h gathered in bf16.
// ---------------------------------------------------------------------------
__global__ __launch_bounds__(64) void k6_agg(const uint32_t* __restrict__ hb32,
                                             const float* __restrict__ a_src,
                                             const float* __restrict__ a_dst,
                                             const int* __restrict__ rowptr,
                                             const int* __restrict__ csr_src,
                                             const float* __restrict__ bias,
                                             float* __restrict__ act) {
    const int node = blockIdx.x;
    const int lane = threadIdx.x;
    const int c0   = lane << 1;
    const int head = lane >> 4;

    const float ad  = a_dst[node * NHEAD + head];
    const int   beg = rowptr[node];
    const int   end = rowptr[node + 1];

    float l = 0.f, acc0 = 0.f, acc1 = 0.f;

    int p = beg;
    for (; p + 4 <= end; p += 4) {
        int s0 = csr_src[p + 0];
        int s1 = csr_src[p + 1];
        int s2 = csr_src[p + 2];
        int s3 = csr_src[p + 3];
        float e0 = a_src[s0 * NHEAD + head] + ad;
        float e1 = a_src[s1 * NHEAD + head] + ad;
        float e2 = a_src[s2 * NHEAD + head] + ad;
        float e3 = a_src[s3 * NHEAD + head] + ad;
        uint32_t u0 = hb32[(size_t)s0 * 64 + lane];
        uint32_t u1 = hb32[(size_t)s1 * 64 + lane];
        uint32_t u2 = hb32[(size_t)s2 * 64 + lane];
        uint32_t u3 = hb32[(size_t)s3 * 64 + lane];
        e0 = (e0 > 0.f) ? e0 : 0.2f * e0;
        e1 = (e1 > 0.f) ? e1 : 0.2f * e1;
        e2 = (e2 > 0.f) ? e2 : 0.2f * e2;
        e3 = (e3 > 0.f) ? e3 : 0.2f * e3;
        float w0 = __expf(e0), w1 = __expf(e1);
        float w2 = __expf(e2), w3 = __expf(e3);
        l += (w0 + w1) + (w2 + w3);
        acc0 = fmaf(w0, bf_lo(u0), acc0);
        acc1 = fmaf(w0, bf_hi(u0), acc1);
        acc0 = fmaf(w1, bf_lo(u1), acc0);
        acc1 = fmaf(w1, bf_hi(u1), acc1);
        acc0 = fmaf(w2, bf_lo(u2), acc0);
        acc1 = fmaf(w2, bf_hi(u2), acc1);
        acc0 = fmaf(w3, bf_lo(u3), acc0);
        acc1 = fmaf(w3, bf_hi(u3), acc1);
    }
    for (; p < end; ++p) {
        int s = csr_src[p];
        float e = a_src[s * NHEAD + head] + ad;
        e = (e > 0.f) ? e : 0.2f * e;
        float w = __expf(e);
        uint32_t u = hb32[(size_t)s * 64 + lane];
        l += w;
        acc0 = fmaf(w, bf_lo(u), acc0);
        acc1 = fmaf(w, bf_hi(u), acc1);
    }

    float inv = 1.f / l;
    float o0 = acc0 * inv + bias[c0];
    float o1 = acc1 * inv + bias[c0 + 1];
    o0 = (o0 > 0.f) ? o0 : (__expf(o0) - 1.f);
    o1 = (o1 > 0.f) ? o1 : (__expf(o1) - 1.f);
    *(float2*)(act + (size_t)node * HC + c0) = make_float2(o0, o1);
}

// ---------------------------------------------------------------------------
// K7: out = act @ lin_W + lin_b   [N,128] @ [128,64]
// ---------------------------------------------------------------------------
__global__ __launch_bounds__(512) void k7_out(const float* __restrict__ act,
                                              const float* __restrict__ linW,
                                              const float* __restrict__ linb,
                                              float* __restrict__ out) {
    __shared__ float sW[HC * OUT_DIM];   // 32 KB
    __shared__ float srow[32 * HC];      // 16 KB
    const int tid   = threadIdx.x;
    const int node0 = blockIdx.x * 32;

    for (int i = tid * 4; i < HC * OUT_DIM; i += 512 * 4)
        *(float4*)(sW + i) = *(const float4*)(linW + i);
    for (int i = tid * 4; i < 32 * HC; i += 512 * 4) {
        int r = i >> 7;
        int node = node0 + r;
        float4 v = make_float4(0.f, 0.f, 0.f, 0.f);
        if (node < N_NODES) v = *(const float4*)(act + (size_t)node * HC + (i & 127));
        *(float4*)(srow + i) = v;
    }
    __syncthreads();

    const int r    = tid >> 4;
    const int colb = (tid & 15) << 2;
    float4 acc = *(const float4*)(linb + colb);
    const float* rp = srow + r * HC;

    #pragma unroll
    for (int k = 0; k < HC; k += 4) {
        float4 xv = *(const float4*)(rp + k);
        float4 w0 = *(const float4*)(sW + (k + 0) * OUT_DIM + colb);
        float4 w1 = *(const float4*)(sW + (k + 1) * OUT_DIM + colb);
        float4 w2 = *(const float4*)(sW + (k + 2) * OUT_DIM + colb);
        float4 w3 = *(const float4*)(sW + (k + 3) * OUT_DIM + colb);
        acc.x += xv.x * w0.x; acc.x += xv.y * w1.x; acc.x += xv.z * w2.x; acc.x += xv.w * w3.x;
        acc.y += xv.x * w0.y; acc.y += xv.y * w1.y; acc.y += xv.z * w2.y; acc.y += xv.w * w3.y;
        acc.z += xv.x * w0.z; acc.z += xv.y * w1.z; acc.z += xv.z * w2.z; acc.z += xv.w * w3.z;
        acc.w += xv.x * w0.w; acc.w += xv.y * w1.w; acc.w += xv.z * w2.w; acc.w += xv.w * w3.w;
    }

    int node = node0 + r;
    if (node < N_NODES)
        *(float4*)(out + (size_t)node * OUT_DIM + colb) = acc;
}

// ---------------------------------------------------------------------------
extern "C" void kernel_launch(void* const* d_in, const int* in_sizes, int n_in,
                              void* d_out, int out_size, void* d_ws, size_t ws_size,
                              hipStream_t stream) {
    (void)in_sizes; (void)n_in; (void)out_size; (void)ws_size;
    const float* x       = (const float*)d_in[0];
    const int*   ei      = (const int*)d_in[1];
    const float* W       = (const float*)d_in[2];
    const float* att_src = (const float*)d_in[3];
    const float* att_dst = (const float*)d_in[4];
    const float* bias    = (const float*)d_in[5];
    const float* linW    = (const float*)d_in[6];
    const float* linb    = (const float*)d_in[7];
    float*       out     = (float*)d_out;

    char*  ws  = (char*)d_ws;
    size_t off = 0;
    auto alloc = [&](size_t bytes) -> void* {
        void* p = ws + off;
        off += (bytes + 255) & ~(size_t)255;
        return p;
    };
    uint16_t* hb     = (uint16_t*)alloc((size_t)N_NODES * HC * 2);
    float*    act    = (float*)alloc((size_t)N_NODES * HC * 4);
    float*    a_src  = (float*)alloc((size_t)N_NODES * NHEAD * 4);
    float*    a_dst  = (float*)alloc((size_t)N_NODES * NHEAD * 4);
    int*      gcount = (int*)alloc((size_t)(NBUK + 1) * 4);
    int*      gcur   = (int*)alloc((size_t)(NBUK + 1) * 4);
    int*      bbase  = (int*)alloc((size_t)(NBUK + 1) * 4);
    int*      rowptr = (int*)alloc((size_t)(N_NODES + 1) * 4);
    uint32_t* binned = (uint32_t*)alloc((size_t)TOT_E * 4);
    int*      csr    = (int*)alloc((size_t)TOT_E * 4);

    hipMemsetAsync(gcount, 0, (size_t)(NBUK + 1) * 4, stream);

    k1_gemm<<<(N_NODES + 63) / 64, 256, 0, stream>>>(x, W, att_src, att_dst,
                                                     hb, a_src, a_dst);
    p1_hist<<<NCHUNK, 256, 0, stream>>>(ei, gcount);
    p2_scan<<<1, 512, 0, stream>>>(gcount, gcur, bbase, rowptr);
    p3_bin<<<NCHUNK, 256, 0, stream>>>(ei, gcur, binned);
    p4_csr<<<NBUK, 256, 0, stream>>>(binned, bbase, rowptr, csr);
    k6_agg<<<N_NODES, 64, 0, stream>>>((const uint32_t*)hb, a_src, a_dst,
                                       rowptr, csr, bias, act);
    k7_out<<<(N_NODES + 31) / 32, 512, 0, stream>>>(act, linW, linb, out);
}

// Round 4
// 279.246 us; speedup vs baseline: 1.9379x; 1.0991x over previous
//
#include <hip/hip_runtime.h>
#include <cstdint>
#include <cstddef>

#define N_NODES 50000
#define N_EDGES 1600000
#define TOT_E   (N_EDGES + N_NODES)
#define IN_DIM  256
#define HC      128
#define NHEAD   4
#define OUT_DIM 64

// bucket-radix CSR build
#define SHIFT   7
#define BSZ     128
#define NBUK    ((N_NODES + BSZ - 1) / BSZ)
#define CHUNK   8192
#define EPT     32
#define NCHUNK  ((TOT_E + CHUNK - 1) / CHUNK)
#define CAP     5120

// k1 MFMA tiling
#define XPAD 264   // bf16 elems per LDS row (256 + 8): row stride 528 B ≡ 4 banks
#define HPAD 132   // fp32 elems per LDS row in epilogue (128 + 4)

typedef __attribute__((ext_vector_type(8))) short bf16x8;
typedef __attribute__((ext_vector_type(4))) float f32x4;

static __device__ __forceinline__ uint16_t f2bf(float f) {
    uint32_t u = __float_as_uint(f);
    uint32_t r = (u + 0x7fffu + ((u >> 16) & 1u)) >> 16;   // RNE
    return (uint16_t)r;
}
static __device__ __forceinline__ float bf_lo(uint32_t u) {
    return __uint_as_float(u << 16);
}
static __device__ __forceinline__ float bf_hi(uint32_t u) {
    return __uint_as_float(u & 0xffff0000u);
}

// ---------------------------------------------------------------------------
// W prep: W fp32 [256][128] -> W^T bf16 [128][256]  (B^T layout for MFMA)
// ---------------------------------------------------------------------------
__global__ __launch_bounds__(256) void w2bf(const float* __restrict__ W,
                                            uint16_t* __restrict__ wt) {
    int idx = blockIdx.x * 256 + threadIdx.x;   // n*256 + k
    int n = idx >> 8, k = idx & 255;
    wt[idx] = f2bf(W[(size_t)k * HC + n]);
}

// ---------------------------------------------------------------------------
// K1 (MFMA): h = x @ W, bf16 inputs, fp32 accum. Block = 4 waves = 64 rows x
// 128 cols; whole K=256 staged once in LDS (bf16). Wave w: rows 16w..16w+15,
// 8 col-tiles, 8 k-steps of mfma_f32_16x16x32_bf16. B^T read from global
// (64 KB, L1/L2-hot, fully coalesced). Epilogue through LDS (reuses x tile):
// bf16 hb store + fused a_src/a_dst (one thread per (row,head); head h owns
// cols 32h..32h+31 so no cross-thread reduction).
// ---------------------------------------------------------------------------
__global__ __launch_bounds__(256) void k1_mfma(const float* __restrict__ x,
                                               const uint16_t* __restrict__ wt,
                                               const float* __restrict__ att_src,
                                               const float* __restrict__ att_dst,
                                               uint16_t* __restrict__ hb,
                                               float* __restrict__ a_src,
                                               float* __restrict__ a_dst) {
    __shared__ char smem[64 * 528];   // 33792 B: xs(bf16 64x264) == hs(f32 64x132)
    __shared__ float att_s[HC], att_d[HC];
    uint16_t* xs = (uint16_t*)smem;
    float*    hs = (float*)smem;

    const int tid  = threadIdx.x;
    const int wave = tid >> 6;
    const int lane = tid & 63;
    const int m    = lane & 15;    // A-row / B-col within 16-tile
    const int q    = lane >> 4;    // k-quad
    const int row0 = blockIdx.x * 64;

    if (tid < HC) { att_s[tid] = att_src[tid]; att_d[tid] = att_dst[tid]; }

    // stage x tile (fp32 -> bf16), coalesced float4
    for (int i = tid * 4; i < 64 * IN_DIM; i += 1024) {
        int r = i >> 8, c = i & 255;
        int gr = row0 + r;
        float4 v = make_float4(0.f, 0.f, 0.f, 0.f);
        if (gr < N_NODES) v = *(const float4*)(x + (size_t)gr * IN_DIM + c);
        uint32_t lo = (uint32_t)f2bf(v.x) | ((uint32_t)f2bf(v.y) << 16);
        uint32_t hi = (uint32_t)f2bf(v.z) | ((uint32_t)f2bf(v.w) << 16);
        *(uint2*)(xs + r * XPAD + c) = make_uint2(lo, hi);
    }
    __syncthreads();

    f32x4 acc[8];
    #pragma unroll
    for (int t = 0; t < 8; ++t) acc[t] = (f32x4){0.f, 0.f, 0.f, 0.f};

    const int arow = wave * 16 + m;
    #pragma unroll
    for (int ks = 0; ks < IN_DIM; ks += 32) {
        bf16x8 a = *(const bf16x8*)(xs + arow * XPAD + ks + q * 8);
        #pragma unroll
        for (int t = 0; t < 8; ++t) {
            bf16x8 b = *(const bf16x8*)(wt + (size_t)(t * 16 + m) * IN_DIM + ks + q * 8);
            acc[t] = __builtin_amdgcn_mfma_f32_16x16x32_bf16(a, b, acc[t], 0, 0, 0);
        }
    }
    __syncthreads();   // xs dead; reuse as hs

    // C/D layout: col = lane&15, row = (lane>>4)*4 + reg
    #pragma unroll
    for (int t = 0; t < 8; ++t)
        #pragma unroll
        for (int r = 0; r < 4; ++r)
            hs[(wave * 16 + q * 4 + r) * HPAD + t * 16 + m] = acc[t][r];
    __syncthreads();

    // pass A: hb bf16 store (coalesced)
    for (int i = tid * 4; i < 64 * HC; i += 1024) {
        int r = i >> 7, c = i & 127;
        if (row0 + r < N_NODES) {
            float4 v = *(const float4*)(hs + r * HPAD + c);
            uint32_t lo = (uint32_t)f2bf(v.x) | ((uint32_t)f2bf(v.y) << 16);
            uint32_t hi = (uint32_t)f2bf(v.z) | ((uint32_t)f2bf(v.w) << 16);
            *(uint2*)(hb + (size_t)(row0 + r) * HC + c) = make_uint2(lo, hi);
        }
    }
    // pass B: attention halves (thread = (row, head))
    {
        int r = tid >> 2, hd = tid & 3;
        if (row0 + r < N_NODES) {
            float s = 0.f, d = 0.f;
            #pragma unroll
            for (int j = 0; j < 32; ++j) {
                float v = hs[r * HPAD + hd * 32 + j];
                s = fmaf(v, att_s[hd * 32 + j], s);
                d = fmaf(v, att_d[hd * 32 + j], d);
            }
            a_src[(row0 + r) * NHEAD + hd] = s;
            a_dst[(row0 + r) * NHEAD + hd] = d;
        }
    }
}

// ---------------------------------------------------------------------------
// P1: bucket histogram
// ---------------------------------------------------------------------------
__global__ __launch_bounds__(256) void p1_hist(const int* __restrict__ ei,
                                               int* __restrict__ gcount) {
    __shared__ int hist[NBUK];
    const int tid = threadIdx.x;
    for (int i = tid; i < NBUK; i += 256) hist[i] = 0;
    __syncthreads();
    const int base = blockIdx.x * CHUNK;
    #pragma unroll 4
    for (int k = 0; k < EPT; ++k) {
        int e = base + k * 256 + tid;
        if (e < TOT_E) {
            int dst = (e < N_EDGES) ? ei[N_EDGES + e] : (e - N_EDGES);
            atomicAdd(&hist[dst >> SHIFT], 1);
        }
    }
    __syncthreads();
    for (int i = tid; i < NBUK; i += 256)
        if (hist[i]) atomicAdd(&gcount[i], hist[i]);
}

// ---------------------------------------------------------------------------
// P2: 1-block scan of bucket counts
// ---------------------------------------------------------------------------
__global__ __launch_bounds__(512) void p2_scan(const int* __restrict__ gcount,
                                               int* __restrict__ gcur,
                                               int* __restrict__ bbase,
                                               int* __restrict__ rowptr) {
    __shared__ int ws[8];
    const int tid  = threadIdx.x;
    const int lane = tid & 63;
    const int wid  = tid >> 6;
    int v = (tid < NBUK) ? gcount[tid] : 0;
    int inc = v;
    #pragma unroll
    for (int d = 1; d < 64; d <<= 1) {
        int t = __shfl_up(inc, d, 64);
        if (lane >= d) inc += t;
    }
    if (lane == 63) ws[wid] = inc;
    __syncthreads();
    int wo = 0;
    for (int w = 0; w < wid; ++w) wo += ws[w];
    if (tid < NBUK) {
        int ex = wo + inc - v;
        gcur[tid]  = ex;
        bbase[tid] = ex;
    }
    if (tid == 0) { bbase[NBUK] = TOT_E; rowptr[N_NODES] = TOT_E; }
}

// ---------------------------------------------------------------------------
// P3: bin edges as packed words: src(16) | dstlocal(7)<<16 | bucket(9)<<23
// ---------------------------------------------------------------------------
__global__ __launch_bounds__(256) void p3_bin(const int* __restrict__ ei,
                                              int* __restrict__ gcur,
                                              uint32_t* __restrict__ binned) {
    __shared__ int hist[NBUK];
    __shared__ int lcur[NBUK];
    const int tid = threadIdx.x;
    for (int i = tid; i < NBUK; i += 256) hist[i] = 0;
    __syncthreads();

    uint32_t wreg[EPT];
    const int base = blockIdx.x * CHUNK;
    #pragma unroll
    for (int k = 0; k < EPT; ++k) {
        int e = base + k * 256 + tid;
        uint32_t word = 0xFFFFFFFFu;
        if (e < TOT_E) {
            int src, dst;
            if (e < N_EDGES) { src = ei[e]; dst = ei[N_EDGES + e]; }
            else             { src = e - N_EDGES; dst = src; }
            int b = dst >> SHIFT;
            word = (uint32_t)src | ((uint32_t)(dst & (BSZ - 1)) << 16)
                 | ((uint32_t)b << 23);
            atomicAdd(&hist[b], 1);
        }
        wreg[k] = word;
    }
    __syncthreads();
    for (int i = tid; i < NBUK; i += 256) {
        int c = hist[i];
        lcur[i] = c ? atomicAdd(&gcur[i], c) : 0;
    }
    __syncthreads();
    #pragma unroll
    for (int k = 0; k < EPT; ++k) {
        uint32_t word = wreg[k];
        if (word != 0xFFFFFFFFu) {
            int b = (int)(word >> 23);
            int pos = atomicAdd(&lcur[b], 1);
            binned[pos] = word;
        }
    }
}

// ---------------------------------------------------------------------------
// P4: per-bucket: LDS stage + 128-node count/scan -> rowptr + csr
// ---------------------------------------------------------------------------
__global__ __launch_bounds__(256) void p4_csr(const uint32_t* __restrict__ binned,
                                              const int* __restrict__ bbase,
                                              int* __restrict__ rowptr,
                                              int* __restrict__ csr_src) {
    __shared__ uint32_t ew[CAP];
    __shared__ int ncnt[BSZ];
    __shared__ int ncur[BSZ];
    __shared__ int wtot;
    const int b    = blockIdx.x;
    const int base = bbase[b];
    const int cnt  = bbase[b + 1] - base;
    const int tid  = threadIdx.x;

    for (int i = tid; i < BSZ; i += 256) ncnt[i] = 0;
    __syncthreads();

    const bool fit = (cnt <= CAP);
    for (int i = tid; i < cnt; i += 256) {
        uint32_t word = binned[base + i];
        if (fit) ew[i] = word;
        atomicAdd(&ncnt[(word >> 16) & (BSZ - 1)], 1);
    }
    __syncthreads();

    int v = 0, inc = 0;
    if (tid < BSZ) {
        v = ncnt[tid];
        inc = v;
        int lane = tid & 63;
        #pragma unroll
        for (int d = 1; d < 64; d <<= 1) {
            int t = __shfl_up(inc, d, 64);
            if (lane >= d) inc += t;
        }
        if (tid == 63) wtot = inc;
    }
    __syncthreads();
    if (tid < BSZ) {
        int ex = inc - v + ((tid >= 64) ? wtot : 0);
        int node = b * BSZ + tid;
        if (node < N_NODES) rowptr[node] = base + ex;
        ncur[tid] = ex;
    }
    __syncthreads();

    for (int i = tid; i < cnt; i += 256) {
        uint32_t word = fit ? ew[i] : binned[base + i];
        int local = (word >> 16) & (BSZ - 1);
        int r = atomicAdd(&ncur[local], 1);
        csr_src[base + r] = (int)(word & 0xFFFFu);
    }
}

// ---------------------------------------------------------------------------
// K6: per-node softmax aggregation + bias + ELU (bf16 h gather)
// ---------------------------------------------------------------------------
__global__ __launch_bounds__(64) void k6_agg(const uint32_t* __restrict__ hb32,
                                             const float* __restrict__ a_src,
                                             const float* __restrict__ a_dst,
                                             const int* __restrict__ rowptr,
                                             const int* __restrict__ csr_src,
                                             const float* __restrict__ bias,
                                             float* __restrict__ act) {
    const int node = blockIdx.x;
    const int lane = threadIdx.x;
    const int c0   = lane << 1;
    const int head = lane >> 4;

    const float ad  = a_dst[node * NHEAD + head];
    const int   beg = rowptr[node];
    const int   end = rowptr[node + 1];

    float l = 0.f, acc0 = 0.f, acc1 = 0.f;

    int p = beg;
    for (; p + 4 <= end; p += 4) {
        int s0 = csr_src[p + 0];
        int s1 = csr_src[p + 1];
        int s2 = csr_src[p + 2];
        int s3 = csr_src[p + 3];
        float e0 = a_src[s0 * NHEAD + head] + ad;
        float e1 = a_src[s1 * NHEAD + head] + ad;
        float e2 = a_src[s2 * NHEAD + head] + ad;
        float e3 = a_src[s3 * NHEAD + head] + ad;
        uint32_t u0 = hb32[(size_t)s0 * 64 + lane];
        uint32_t u1 = hb32[(size_t)s1 * 64 + lane];
        uint32_t u2 = hb32[(size_t)s2 * 64 + lane];
        uint32_t u3 = hb32[(size_t)s3 * 64 + lane];
        e0 = (e0 > 0.f) ? e0 : 0.2f * e0;
        e1 = (e1 > 0.f) ? e1 : 0.2f * e1;
        e2 = (e2 > 0.f) ? e2 : 0.2f * e2;
        e3 = (e3 > 0.f) ? e3 : 0.2f * e3;
        float w0 = __expf(e0), w1 = __expf(e1);
        float w2 = __expf(e2), w3 = __expf(e3);
        l += (w0 + w1) + (w2 + w3);
        acc0 = fmaf(w0, bf_lo(u0), acc0);
        acc1 = fmaf(w0, bf_hi(u0), acc1);
        acc0 = fmaf(w1, bf_lo(u1), acc0);
        acc1 = fmaf(w1, bf_hi(u1), acc1);
        acc0 = fmaf(w2, bf_lo(u2), acc0);
        acc1 = fmaf(w2, bf_hi(u2), acc1);
        acc0 = fmaf(w3, bf_lo(u3), acc0);
        acc1 = fmaf(w3, bf_hi(u3), acc1);
    }
    for (; p < end; ++p) {
        int s = csr_src[p];
        float e = a_src[s * NHEAD + head] + ad;
        e = (e > 0.f) ? e : 0.2f * e;
        float w = __expf(e);
        uint32_t u = hb32[(size_t)s * 64 + lane];
        l += w;
        acc0 = fmaf(w, bf_lo(u), acc0);
        acc1 = fmaf(w, bf_hi(u), acc1);
    }

    float inv = 1.f / l;
    float o0 = acc0 * inv + bias[c0];
    float o1 = acc1 * inv + bias[c0 + 1];
    o0 = (o0 > 0.f) ? o0 : (__expf(o0) - 1.f);
    o1 = (o1 > 0.f) ? o1 : (__expf(o1) - 1.f);
    *(float2*)(act + (size_t)node * HC + c0) = make_float2(o0, o1);
}

// ---------------------------------------------------------------------------
// K7: out = act @ lin_W + lin_b   [N,128] @ [128,64]
// ---------------------------------------------------------------------------
__global__ __launch_bounds__(512) void k7_out(const float* __restrict__ act,
                                              const float* __restrict__ linW,
                                              const float* __restrict__ linb,
                                              float* __restrict__ out) {
    __shared__ float sW[HC * OUT_DIM];   // 32 KB
    __shared__ float srow[32 * HC];      // 16 KB
    const int tid   = threadIdx.x;
    const int node0 = blockIdx.x * 32;

    for (int i = tid * 4; i < HC * OUT_DIM; i += 512 * 4)
        *(float4*)(sW + i) = *(const float4*)(linW + i);
    for (int i = tid * 4; i < 32 * HC; i += 512 * 4) {
        int r = i >> 7;
        int node = node0 + r;
        float4 v = make_float4(0.f, 0.f, 0.f, 0.f);
        if (node < N_NODES) v = *(const float4*)(act + (size_t)node * HC + (i & 127));
        *(float4*)(srow + i) = v;
    }
    __syncthreads();

    const int r    = tid >> 4;
    const int colb = (tid & 15) << 2;
    float4 acc = *(const float4*)(linb + colb);
    const float* rp = srow + r * HC;

    #pragma unroll
    for (int k = 0; k < HC; k += 4) {
        float4 xv = *(const float4*)(rp + k);
        float4 w0 = *(const float4*)(sW + (k + 0) * OUT_DIM + colb);
        float4 w1 = *(const float4*)(sW + (k + 1) * OUT_DIM + colb);
        float4 w2 = *(const float4*)(sW + (k + 2) * OUT_DIM + colb);
        float4 w3 = *(const float4*)(sW + (k + 3) * OUT_DIM + colb);
        acc.x += xv.x * w0.x; acc.x += xv.y * w1.x; acc.x += xv.z * w2.x; acc.x += xv.w * w3.x;
        acc.y += xv.x * w0.y; acc.y += xv.y * w1.y; acc.y += xv.z * w2.y; acc.y += xv.w * w3.y;
        acc.z += xv.x * w0.z; acc.z += xv.y * w1.z; acc.z += xv.z * w2.z; acc.z += xv.w * w3.z;
        acc.w += xv.x * w0.w; acc.w += xv.y * w1.w; acc.w += xv.z * w2.w; acc.w += xv.w * w3.w;
    }

    int node = node0 + r;
    if (node < N_NODES)
        *(float4*)(out + (size_t)node * OUT_DIM + colb) = acc;
}

// ---------------------------------------------------------------------------
extern "C" void kernel_launch(void* const* d_in, const int* in_sizes, int n_in,
                              void* d_out, int out_size, void* d_ws, size_t ws_size,
                              hipStream_t stream) {
    (void)in_sizes; (void)n_in; (void)out_size; (void)ws_size;
    const float* x       = (const float*)d_in[0];
    const int*   ei      = (const int*)d_in[1];
    const float* W       = (const float*)d_in[2];
    const float* att_src = (const float*)d_in[3];
    const float* att_dst = (const float*)d_in[4];
    const float* bias    = (const float*)d_in[5];
    const float* linW    = (const float*)d_in[6];
    const float* linb    = (const float*)d_in[7];
    float*       out     = (float*)d_out;

    char*  ws  = (char*)d_ws;
    size_t off = 0;
    auto alloc = [&](size_t bytes) -> void* {
        void* p = ws + off;
        off += (bytes + 255) & ~(size_t)255;
        return p;
    };
    uint16_t* hb     = (uint16_t*)alloc((size_t)N_NODES * HC * 2);
    uint16_t* wt     = (uint16_t*)alloc((size_t)HC * IN_DIM * 2);
    float*    act    = (float*)alloc((size_t)N_NODES * HC * 4);
    float*    a_src  = (float*)alloc((size_t)N_NODES * NHEAD * 4);
    float*    a_dst  = (float*)alloc((size_t)N_NODES * NHEAD * 4);
    int*      gcount = (int*)alloc((size_t)(NBUK + 1) * 4);
    int*      gcur   = (int*)alloc((size_t)(NBUK + 1) * 4);
    int*      bbase  = (int*)alloc((size_t)(NBUK + 1) * 4);
    int*      rowptr = (int*)alloc((size_t)(N_NODES + 1) * 4);
    uint32_t* binned = (uint32_t*)alloc((size_t)TOT_E * 4);
    int*      csr    = (int*)alloc((size_t)TOT_E * 4);

    hipMemsetAsync(gcount, 0, (size_t)(NBUK + 1) * 4, stream);

    w2bf<<<(HC * IN_DIM) / 256, 256, 0, stream>>>(W, wt);
    k1_mfma<<<(N_NODES + 63) / 64, 256, 0, stream>>>(x, wt, att_src, att_dst,
                                                     hb, a_src, a_dst);
    p1_hist<<<NCHUNK, 256, 0, stream>>>(ei, gcount);
    p2_scan<<<1, 512, 0, stream>>>(gcount, gcur, bbase, rowptr);
    p3_bin<<<NCHUNK, 256, 0, stream>>>(ei, gcur, binned);
    p4_csr<<<NBUK, 256, 0, stream>>>(binned, bbase, rowptr, csr);
    k6_agg<<<N_NODES, 64, 0, stream>>>((const uint32_t*)hb, a_src, a_dst,
                                       rowptr, csr, bias, act);
    k7_out<<<(N_NODES + 31) / 32, 512, 0, stream>>>(act, linW, linb, out);
}